// Round 1
// baseline (1817.709 us; speedup 1.0000x reference)
//
#include <hip/hip_runtime.h>
#include <hip/hip_bf16.h>

// Problem constants
#define NROWS 32768   // B*H*W = 32*32*32
#define CDIM  256
#define KCODES 8192
#define HWPB  1024    // H*W per batch
#define OUT_ELEMS 8388608   // 32*256*32*32
// d_out layout: [0, 8388608) = out BCHW, [8388608] = loss, [8388609, +32768) = indices (as float)

// ---------------- inv-norm of codebook rows ----------------
__global__ __launch_bounds__(256) void vq_invnorm_kernel(
    const float* __restrict__ e, float* __restrict__ invn) {
  const int row  = blockIdx.x * 4 + (threadIdx.x >> 6);
  const int lane = threadIdx.x & 63;
  const float4 v = *reinterpret_cast<const float4*>(e + (size_t)row * CDIM + lane * 4);
  float s = v.x * v.x + v.y * v.y + v.z * v.z + v.w * v.w;
  #pragma unroll
  for (int o = 32; o > 0; o >>= 1) s += __shfl_down(s, o);
  if (lane == 0) invn[row] = 1.0f / fmaxf(sqrtf(s), 1e-12f);
}

// ---------------- fused fp32 GEMM + argmax ----------------
// Tile: BM=128 rows x BN=128 codes, 256 threads, 8x8 micro-tile, KC=8 c-chunk.
// Grid: (NROWS/128, 2) -- K split in halves for 512 blocks (2 blocks/CU).
#define BM 128
#define BN 128
#define KC 8

__global__ __launch_bounds__(256) void vq_dist_argmax_kernel(
    const float* __restrict__ z, const float* __restrict__ e,
    const float* __restrict__ invn,
    float* __restrict__ bestval, int* __restrict__ bestidx) {
  __shared__ float as[KC][BM];
  __shared__ float bs[KC][BN + 4];
  __shared__ float rv[BM][16];
  __shared__ int   ri[BM][16];

  const int t  = threadIdx.x;
  const int tx = t & 15;   // code group
  const int ty = t >> 4;   // row group
  const int n0 = blockIdx.x * BM;
  const int b   = n0 >> 10;      // batch (tiles never straddle a batch: 128 | 1024)
  const int hw0 = n0 & 1023;
  const float* zbase = z + (size_t)b * (CDIM * HWPB) + hw0;  // + c*1024 + m
  const int kbeg = blockIdx.y * (KCODES / 2);

  float bv[8]; int bi[8];
  #pragma unroll
  for (int i = 0; i < 8; ++i) { bv[i] = -3.4e38f; bi[i] = 0; }

  // loader coords
  const int lm  = t & 127;        // as: row within tile
  const int lc0 = t >> 7;         // as: base cc (0/1), strided by 2
  const int bkk = t >> 2;         // bs: code within tile (2 passes of 64)
  const int bcc = (t & 3) * 2;    // bs: c pair

  for (int kt = 0; kt < (KCODES / 2) / BN; ++kt) {
    const int k0 = kbeg + kt * BN;
    float acc[8][8];
    #pragma unroll
    for (int i = 0; i < 8; ++i)
      #pragma unroll
      for (int j = 0; j < 8; ++j) acc[i][j] = 0.f;

    for (int c0 = 0; c0 < CDIM; c0 += KC) {
      // stage A: 8x128 floats, 4 per thread, coalesced over m
      #pragma unroll
      for (int p = 0; p < 4; ++p) {
        const int cc = lc0 + 2 * p;
        as[cc][lm] = zbase[(size_t)(c0 + cc) * HWPB + lm];
      }
      // stage B (transposed): 8x128 floats via float2, 2 passes
      #pragma unroll
      for (int p = 0; p < 2; ++p) {
        const int kk = bkk + 64 * p;
        const float2 v = *reinterpret_cast<const float2*>(
            e + (size_t)(k0 + kk) * CDIM + c0 + bcc);
        bs[bcc][kk]     = v.x;
        bs[bcc + 1][kk] = v.y;
      }
      __syncthreads();
      #pragma unroll
      for (int cc = 0; cc < KC; ++cc) {
        float a[8], bb[8];
        #pragma unroll
        for (int i = 0; i < 8; ++i) a[i]  = as[cc][ty * 8 + i];
        #pragma unroll
        for (int j = 0; j < 8; ++j) bb[j] = bs[cc][tx * 8 + j];
        #pragma unroll
        for (int i = 0; i < 8; ++i)
          #pragma unroll
          for (int j = 0; j < 8; ++j)
            acc[i][j] = fmaf(a[i], bb[j], acc[i][j]);
      }
      __syncthreads();
    }

    // scale by codebook inv-norm, update running argmax (first-max kept)
    #pragma unroll
    for (int j = 0; j < 8; ++j) {
      const int k = k0 + tx * 8 + j;
      const float inv = invn[k];
      #pragma unroll
      for (int i = 0; i < 8; ++i) {
        const float v = acc[i][j] * inv;
        if (v > bv[i]) { bv[i] = v; bi[i] = k; }
      }
    }
  }

  // reduce across the 16 tx threads sharing each row
  #pragma unroll
  for (int i = 0; i < 8; ++i) { rv[ty * 8 + i][tx] = bv[i]; ri[ty * 8 + i][tx] = bi[i]; }
  __syncthreads();
  if (t < BM) {
    float best = rv[t][0]; int bid = ri[t][0];
    #pragma unroll
    for (int x = 1; x < 16; ++x) {
      const float v = rv[t][x]; const int id = ri[t][x];
      if (v > best || (v == best && id < bid)) { best = v; bid = id; }
    }
    bestval[blockIdx.y * NROWS + n0 + t] = best;
    bestidx[blockIdx.y * NROWS + n0 + t] = bid;
  }
}

// ---------------- gather + out write + loss partial ----------------
// One block per 64 rows (same batch). Coalesced z reads / out writes.
__global__ __launch_bounds__(256) void vq_gather_loss_kernel(
    const float* __restrict__ z, const float* __restrict__ e,
    const float* __restrict__ bestval, const int* __restrict__ bestidx,
    float* __restrict__ out, float* __restrict__ lossacc) {
  __shared__ int sidx[64];
  const int t  = threadIdx.x;
  const int n0 = blockIdx.x * 64;
  if (t < 64) {
    const int n = n0 + t;
    const float v0 = bestval[n], v1 = bestval[NROWS + n];
    const int   i0 = bestidx[n], i1 = bestidx[NROWS + n];
    const int id = (v1 > v0) ? i1 : i0;  // tie -> lower half (smaller index)
    sidx[t] = id;
    out[OUT_ELEMS + 1 + n] = (float)id;
  }
  __syncthreads();
  const int b    = n0 >> 10;
  const int hw0  = n0 & 1023;
  const int nsub = t & 63;
  const int cg   = t >> 6;
  const float* erow = e + (size_t)sidx[nsub] * CDIM;
  float lsum = 0.f;
  for (int c = cg; c < CDIM; c += 4) {
    const float  v  = erow[c];
    const size_t off = (size_t)b * (CDIM * HWPB) + (size_t)c * HWPB + hw0 + nsub;
    const float  d  = v - z[off];
    lsum += d * d;
    out[off] = v;
  }
  #pragma unroll
  for (int o = 32; o > 0; o >>= 1) lsum += __shfl_down(lsum, o);
  __shared__ float wsum[4];
  if ((t & 63) == 0) wsum[t >> 6] = lsum;
  __syncthreads();
  if (t == 0) atomicAdd(lossacc, wsum[0] + wsum[1] + wsum[2] + wsum[3]);
}

__global__ void vq_finalize_kernel(const float* __restrict__ lossacc,
                                   float* __restrict__ out) {
  out[OUT_ELEMS] = 1.25f * lossacc[0] / (float)OUT_ELEMS;
}

extern "C" void kernel_launch(void* const* d_in, const int* in_sizes, int n_in,
                              void* d_out, int out_size, void* d_ws, size_t ws_size,
                              hipStream_t stream) {
  const float* z = (const float*)d_in[0];        // [32,256,32,32]
  const float* e = (const float*)d_in[1];        // [8192,256]
  float* out = (float*)d_out;

  // workspace layout (floats): invn[8192] | bestval[2*32768] | bestidx[2*32768] | lossacc[1]
  float* invn    = (float*)d_ws;
  float* bestval = invn + KCODES;
  int*   bestidx = (int*)(bestval + 2 * NROWS);
  float* lossacc = (float*)(bestidx + 2 * NROWS);

  hipMemsetAsync(lossacc, 0, sizeof(float), stream);

  vq_invnorm_kernel<<<KCODES / 4, 256, 0, stream>>>(e, invn);

  dim3 grid(NROWS / BM, 2);
  vq_dist_argmax_kernel<<<grid, 256, 0, stream>>>(z, e, invn, bestval, bestidx);

  vq_gather_loss_kernel<<<NROWS / 64, 256, 0, stream>>>(z, e, bestval, bestidx,
                                                        out, lossacc);
  vq_finalize_kernel<<<1, 1, 0, stream>>>(lossacc, out);
}